// Round 1
// baseline (1310.007 us; speedup 1.0000x reference)
//
#include <hip/hip_runtime.h>

typedef unsigned short u16;
typedef unsigned int u32;
typedef __bf16 bf16x8 __attribute__((ext_vector_type(8)));
typedef float f32x4 __attribute__((ext_vector_type(4)));

#define S_LEN 2048
#define NH 16
#define HD 128

__device__ __forceinline__ u16 f2bf(float x) {
  u32 u = __builtin_bit_cast(u32, x);
  u32 r = u + 0x7FFFu + ((u >> 16) & 1u);  // RNE
  return (u16)(r >> 16);
}
__device__ __forceinline__ float bf2f(u16 b) {
  return __builtin_bit_cast(float, (u32)b << 16);
}

// ---------------- fp32 -> bf16 conversion (vectorized, G13) ----------------
__global__ void cvt_f32_bf16(const float* __restrict__ in, u16* __restrict__ out, int n4) {
  int i = blockIdx.x * 256 + threadIdx.x;
  if (i >= n4) return;
  float4 v = ((const float4*)in)[i];
  ushort4 o;
  o.x = f2bf(v.x); o.y = f2bf(v.y); o.z = f2bf(v.z); o.w = f2bf(v.w);
  ((ushort4*)out)[i] = o;
}

// ---------------- RoPE cos/sin table: tab[0..S*64) = cos, [S*64..) = sin ----
__global__ void build_tab(float* __restrict__ tab) {
  int t = blockIdx.x * 256 + threadIdx.x;   // S*64 = 131072 threads
  int s = t >> 6, j = t & 63;
  // inv_freq = 10000^(-j/64) = 2^(-j*log2(10000)/64)
  float inv = exp2f(-(float)j * 0.20762050593045083f);
  float ang = (float)s * inv;
  tab[t] = cosf(ang);
  tab[131072 + t] = sinf(ang);
}

// ---------------- GEMM: C[M,N] = A[M,K] * B[N,K]^T, bf16 in, fp32 acc -------
// m97 structure: 128x128 tile, BK=32, 4 waves (2x2), global_load_lds width 16.
__device__ __forceinline__ void storeC(u16* p, float v) { *p = f2bf(v); }
__device__ __forceinline__ void storeC(float* p, float v) { *p = v; }

template <typename OutT>
__global__ __launch_bounds__(256) void gemm_bt(const u16* __restrict__ A, const u16* __restrict__ B,
                                               OutT* __restrict__ C, int M, int N, int K) {
  __shared__ alignas(16) u16 As[128][32];
  __shared__ alignas(16) u16 Bs[128][32];
  const int tid = threadIdx.x;
  const int lane = tid & 63;
  const int w = tid >> 6;
  const int wr = w >> 1, wc = w & 1;
  const int g = lane >> 4, c = lane & 15;
  const size_t rowBase = (size_t)blockIdx.y * 128;
  const size_t colBase = (size_t)blockIdx.x * 128;

  f32x4 acc[4][4];
#pragma unroll
  for (int m = 0; m < 4; ++m)
#pragma unroll
    for (int n = 0; n < 4; ++n) acc[m][n] = f32x4{0.f, 0.f, 0.f, 0.f};

  const u16* Ag = A + rowBase * (size_t)K;
  const u16* Bg = B + colBase * (size_t)K;
  const int srow = lane >> 2;          // 0..15 within chunk
  const int scol = (lane & 3) * 8;     // k offset (elements)

  for (int k0 = 0; k0 < K; k0 += 32) {
#pragma unroll
    for (int p = 0; p < 2; ++p) {
      const int ch = w * 2 + p;        // 0..7, each = 16 rows = 1KB
      const u16* ga = Ag + (size_t)(ch * 16 + srow) * K + k0 + scol;
      const u16* gb = Bg + (size_t)(ch * 16 + srow) * K + k0 + scol;
      __builtin_amdgcn_global_load_lds(
          (const __attribute__((address_space(1))) void*)ga,
          (__attribute__((address_space(3))) void*)((char*)&As[0][0] + ch * 1024), 16, 0, 0);
      __builtin_amdgcn_global_load_lds(
          (const __attribute__((address_space(1))) void*)gb,
          (__attribute__((address_space(3))) void*)((char*)&Bs[0][0] + ch * 1024), 16, 0, 0);
    }
    __syncthreads();   // drains vmcnt before barrier (compiler-inserted)
    bf16x8 af[4], bfr[4];
#pragma unroll
    for (int m = 0; m < 4; ++m) af[m] = *(const bf16x8*)&As[wr * 64 + m * 16 + c][g * 8];
#pragma unroll
    for (int n = 0; n < 4; ++n) bfr[n] = *(const bf16x8*)&Bs[wc * 64 + n * 16 + c][g * 8];
#pragma unroll
    for (int m = 0; m < 4; ++m)
#pragma unroll
      for (int n = 0; n < 4; ++n)
        acc[m][n] = __builtin_amdgcn_mfma_f32_16x16x32_bf16(af[m], bfr[n], acc[m][n], 0, 0, 0);
    __syncthreads();
  }

#pragma unroll
  for (int m = 0; m < 4; ++m)
#pragma unroll
    for (int n = 0; n < 4; ++n) {
      size_t row = rowBase + wr * 64 + m * 16 + g * 4;
      size_t col = colBase + wc * 64 + n * 16 + c;
#pragma unroll
      for (int r = 0; r < 4; ++r)
        storeC(&C[(row + r) * (size_t)N + col], acc[m][n][r]);
    }
}

// ---------------- RoPE on q,k; writes Q,K in [B,H,S,HD] --------------------
__global__ void rope_qk(const u16* __restrict__ qkv, const float* __restrict__ tab,
                        u16* __restrict__ Q, u16* __restrict__ K) {
  int idx = blockIdx.x * 256 + threadIdx.x;  // ((b*NH+h)*S + s)*64 + j, 2^23 total
  int j = idx & 63;
  int s = (idx >> 6) & (S_LEN - 1);
  int h = (idx >> 17) & (NH - 1);
  int b = idx >> 21;
  float cs = tab[s * 64 + j];
  float sn = tab[131072 + s * 64 + j];
  size_t qbase = (((size_t)(b * S_LEN + s) * 3 + 0) * NH + h) * HD;
  size_t kbase = qbase + (size_t)NH * HD;
  size_t o = ((size_t)(b * NH + h) * S_LEN + s) * HD;
  float q1 = bf2f(qkv[qbase + j]),  q2 = bf2f(qkv[qbase + j + 64]);
  Q[o + j]      = f2bf(q1 * cs - q2 * sn);
  Q[o + j + 64] = f2bf(q2 * cs + q1 * sn);
  float k1 = bf2f(qkv[kbase + j]), k2 = bf2f(qkv[kbase + j + 64]);
  K[o + j]      = f2bf(k1 * cs - k2 * sn);
  K[o + j + 64] = f2bf(k2 * cs + k1 * sn);
}

// ---------------- V transpose: qkv v-slot -> Vt [B,H,HD,S] -----------------
__global__ void v_transpose(const u16* __restrict__ qkv, u16* __restrict__ Vt) {
  __shared__ u16 t[32][33];
  int bh = blockIdx.z;
  int s0 = blockIdx.x * 32;
  int d0 = blockIdx.y * 32;
  int b = bh >> 4, h = bh & 15;
  int col = threadIdx.x & 31;
  int row = threadIdx.x >> 5;  // 0..7
#pragma unroll
  for (int i = 0; i < 4; ++i) {
    int s = row + i * 8;
    t[s][col] = qkv[(((size_t)(b * S_LEN + s0 + s) * 3 + 2) * NH + h) * HD + d0 + col];
  }
  __syncthreads();
  size_t vb = ((size_t)bh * HD + d0) * S_LEN + s0;
#pragma unroll
  for (int i = 0; i < 4; ++i) {
    int d = row + i * 8;
    Vt[vb + (size_t)d * S_LEN + col] = t[col][d];
  }
}

// ---------------- causal flash attention ----------------------------------
// block = 4 waves; block owns (b,h, 64 q-rows); wave owns 16 q-rows.
// QK^T: A=Q frags, B=K rows (B^T pattern). PV: P via wave-private LDS, B=Vt rows.
__global__ __launch_bounds__(256) void attn_fwd(const u16* __restrict__ Q, const u16* __restrict__ K,
                                                const u16* __restrict__ Vt, u16* __restrict__ O) {
  __shared__ alignas(16) u16 P_lds[4][16][32];
  const int tid = threadIdx.x;
  const int lane = tid & 63;
  const int w = tid >> 6;
  const int g = lane >> 4, c = lane & 15;
  const int qt = blockIdx.x;
  const int bh = blockIdx.y;

  const u16* Qb = Q + (size_t)bh * S_LEN * HD;
  const u16* Kb = K + (size_t)bh * S_LEN * HD;
  const u16* Vb = Vt + (size_t)bh * HD * S_LEN;

  const int q0 = qt * 64 + w * 16;

  bf16x8 qf[4];
#pragma unroll
  for (int kb = 0; kb < 4; ++kb)
    qf[kb] = *(const bf16x8*)&Qb[(size_t)(q0 + c) * HD + kb * 32 + g * 8];

  f32x4 acc[8];
#pragma unroll
  for (int cb = 0; cb < 8; ++cb) acc[cb] = f32x4{0.f, 0.f, 0.f, 0.f};
  float m_i[4], l_i[4];
#pragma unroll
  for (int r = 0; r < 4; ++r) { m_i[r] = -1e30f; l_i[r] = 0.f; }

  const float scale = 0.08838834764831845f;  // 1/sqrt(128)
  const int nsteps = (q0 + 16 + 31) >> 5;

  for (int st = 0; st < nsteps; ++st) {
    const int kv0 = st * 32;
    f32x4 s0 = f32x4{0.f, 0.f, 0.f, 0.f};
    f32x4 s1 = f32x4{0.f, 0.f, 0.f, 0.f};
#pragma unroll
    for (int kb = 0; kb < 4; ++kb) {
      bf16x8 k0f = *(const bf16x8*)&Kb[(size_t)(kv0 + c) * HD + kb * 32 + g * 8];
      bf16x8 k1f = *(const bf16x8*)&Kb[(size_t)(kv0 + 16 + c) * HD + kb * 32 + g * 8];
      s0 = __builtin_amdgcn_mfma_f32_16x16x32_bf16(qf[kb], k0f, s0, 0, 0, 0);
      s1 = __builtin_amdgcn_mfma_f32_16x16x32_bf16(qf[kb], k1f, s1, 0, 0, 0);
    }
    float p0[4], p1[4], alpha[4];
#pragma unroll
    for (int r = 0; r < 4; ++r) {
      int qrow = q0 + g * 4 + r;
      float v0 = (kv0 + c <= qrow) ? s0[r] * scale : -1e30f;
      float v1 = (kv0 + 16 + c <= qrow) ? s1[r] * scale : -1e30f;
      float mx = fmaxf(v0, v1);
      mx = fmaxf(mx, __shfl_xor(mx, 1));
      mx = fmaxf(mx, __shfl_xor(mx, 2));
      mx = fmaxf(mx, __shfl_xor(mx, 4));
      mx = fmaxf(mx, __shfl_xor(mx, 8));
      float mn = fmaxf(m_i[r], mx);
      alpha[r] = __expf(m_i[r] - mn);
      p0[r] = __expf(v0 - mn);
      p1[r] = __expf(v1 - mn);
      float rs = p0[r] + p1[r];
      rs += __shfl_xor(rs, 1);
      rs += __shfl_xor(rs, 2);
      rs += __shfl_xor(rs, 4);
      rs += __shfl_xor(rs, 8);
      l_i[r] = l_i[r] * alpha[r] + rs;
      m_i[r] = mn;
    }
#pragma unroll
    for (int cb = 0; cb < 8; ++cb)
#pragma unroll
      for (int r = 0; r < 4; ++r) acc[cb][r] *= alpha[r];
#pragma unroll
    for (int r = 0; r < 4; ++r) {
      P_lds[w][g * 4 + r][c]      = f2bf(p0[r]);
      P_lds[w][g * 4 + r][16 + c] = f2bf(p1[r]);
    }
    bf16x8 pa = *(const bf16x8*)&P_lds[w][c][g * 8];
#pragma unroll
    for (int cb = 0; cb < 8; ++cb) {
      bf16x8 vf = *(const bf16x8*)&Vb[(size_t)(cb * 16 + c) * S_LEN + kv0 + g * 8];
      acc[cb] = __builtin_amdgcn_mfma_f32_16x16x32_bf16(pa, vf, acc[cb], 0, 0, 0);
    }
  }

  float inv[4];
#pragma unroll
  for (int r = 0; r < 4; ++r) inv[r] = 1.0f / l_i[r];
  const int b = bh >> 4, h = bh & 15;
#pragma unroll
  for (int cb = 0; cb < 8; ++cb)
#pragma unroll
    for (int r = 0; r < 4; ++r) {
      int qrow = q0 + g * 4 + r;
      O[(((size_t)b * S_LEN + qrow) * NH + h) * HD + cb * 16 + c] = f2bf(acc[cb][r] * inv[r]);
    }
}

// ---------------------------------------------------------------------------
extern "C" void kernel_launch(void* const* d_in, const int* in_sizes, int n_in,
                              void* d_out, int out_size, void* d_ws, size_t ws_size,
                              hipStream_t stream) {
  const float* x    = (const float*)d_in[0];
  const float* wqkv = (const float*)d_in[1];
  const float* wo   = (const float*)d_in[2];
  float* out = (float*)d_out;
  char* ws = (char*)d_ws;

  // ws layout (192 MiB):
  u16*  xb    = (u16*)(ws + 0);            // 33,554,432  (reused as attn out later)
  u16*  wqkvb = (u16*)(ws + 33554432);     // 25,165,824
  float* tab  = (float*)(ws + 58720256);   //  1,048,576 (unioned with wob)
  u16*  wob   = (u16*)(ws + 58720256);     //  8,388,608 (written AFTER rope consumes tab)
  u16*  qkvb  = (u16*)(ws + 67108864);     // 100,663,296
  u16*  Vt    = (u16*)(ws + 167772160);    // 33,554,432 -> end 201,326,592
  u16*  attn  = (u16*)(ws + 0);
  // Q/K (rope'd) live in d_out (64 MiB), dead before GEMM2 writes it.
  u16*  Qr = (u16*)d_out;
  u16*  Kr = (u16*)d_out + 16777216;

  cvt_f32_bf16<<<16384, 256, 0, stream>>>(x, xb, 16777216 / 4);
  cvt_f32_bf16<<<12288, 256, 0, stream>>>(wqkv, wqkvb, 12582912 / 4);
  build_tab<<<512, 256, 0, stream>>>(tab);

  // qkv = x @ wqkv^T : M=8192, N=6144, K=2048
  gemm_bt<u16><<<dim3(48, 64), 256, 0, stream>>>(xb, wqkvb, qkvb, 8192, 6144, 2048);

  rope_qk<<<32768, 256, 0, stream>>>(qkvb, tab, Qr, Kr);
  v_transpose<<<dim3(64, 4, 64), 256, 0, stream>>>(qkvb, Vt);

  cvt_f32_bf16<<<4096, 256, 0, stream>>>(wo, wob, 4194304 / 4);  // tab dead now

  attn_fwd<<<dim3(32, 64), 256, 0, stream>>>(Qr, Kr, Vt, attn);

  // out = attn @ wo^T : M=8192, N=2048, K=2048
  gemm_bt<float><<<dim3(16, 64), 256, 0, stream>>>(attn, wob, out, 8192, 2048, 2048);
}

// Round 2
// 1017.436 us; speedup vs baseline: 1.2876x; 1.2876x over previous
//
#include <hip/hip_runtime.h>

typedef unsigned short u16;
typedef unsigned int u32;
typedef __bf16 bf16x8 __attribute__((ext_vector_type(8)));
typedef float f32x4 __attribute__((ext_vector_type(4)));

#define S_LEN 2048
#define NH 16
#define HD 128

__device__ __forceinline__ u16 f2bf(float x) {
  u32 u = __builtin_bit_cast(u32, x);
  u32 r = u + 0x7FFFu + ((u >> 16) & 1u);  // RNE
  return (u16)(r >> 16);
}
__device__ __forceinline__ float bf2f(u16 b) {
  return __builtin_bit_cast(float, (u32)b << 16);
}

// ---------------- fp32 -> bf16 conversion (vectorized, G13) ----------------
__global__ void cvt_f32_bf16(const float* __restrict__ in, u16* __restrict__ out, int n4) {
  int i = blockIdx.x * 256 + threadIdx.x;
  if (i >= n4) return;
  float4 v = ((const float4*)in)[i];
  ushort4 o;
  o.x = f2bf(v.x); o.y = f2bf(v.y); o.z = f2bf(v.z); o.w = f2bf(v.w);
  ((ushort4*)out)[i] = o;
}

// ---------------- RoPE cos/sin table: tab[0..S*64) = cos, [S*64..) = sin ----
__global__ void build_tab(float* __restrict__ tab) {
  int t = blockIdx.x * 256 + threadIdx.x;   // S*64 = 131072 threads
  int s = t >> 6, j = t & 63;
  float inv = exp2f(-(float)j * 0.20762050593045083f);
  float ang = (float)s * inv;
  tab[t] = cosf(ang);
  tab[131072 + t] = sinf(ang);
}

// ---------------- GEMM: C[M,N] = A[M,K] * B[N,K]^T, bf16 in, fp32 acc -------
__device__ __forceinline__ void storeC(u16* p, float v) { *p = f2bf(v); }
__device__ __forceinline__ void storeC(float* p, float v) { *p = v; }

template <typename OutT>
__global__ __launch_bounds__(256) void gemm_bt(const u16* __restrict__ A, const u16* __restrict__ B,
                                               OutT* __restrict__ C, int M, int N, int K) {
  __shared__ alignas(16) u16 As[128][32];
  __shared__ alignas(16) u16 Bs[128][32];
  const int tid = threadIdx.x;
  const int lane = tid & 63;
  const int w = tid >> 6;
  const int wr = w >> 1, wc = w & 1;
  const int g = lane >> 4, c = lane & 15;
  const size_t rowBase = (size_t)blockIdx.y * 128;
  const size_t colBase = (size_t)blockIdx.x * 128;

  f32x4 acc[4][4];
#pragma unroll
  for (int m = 0; m < 4; ++m)
#pragma unroll
    for (int n = 0; n < 4; ++n) acc[m][n] = f32x4{0.f, 0.f, 0.f, 0.f};

  const u16* Ag = A + rowBase * (size_t)K;
  const u16* Bg = B + colBase * (size_t)K;
  const int srow = lane >> 2;
  const int scol = (lane & 3) * 8;

  for (int k0 = 0; k0 < K; k0 += 32) {
#pragma unroll
    for (int p = 0; p < 2; ++p) {
      const int ch = w * 2 + p;
      const u16* ga = Ag + (size_t)(ch * 16 + srow) * K + k0 + scol;
      const u16* gb = Bg + (size_t)(ch * 16 + srow) * K + k0 + scol;
      __builtin_amdgcn_global_load_lds(
          (const __attribute__((address_space(1))) void*)ga,
          (__attribute__((address_space(3))) void*)((char*)&As[0][0] + ch * 1024), 16, 0, 0);
      __builtin_amdgcn_global_load_lds(
          (const __attribute__((address_space(1))) void*)gb,
          (__attribute__((address_space(3))) void*)((char*)&Bs[0][0] + ch * 1024), 16, 0, 0);
    }
    __syncthreads();
    bf16x8 af[4], bfr[4];
#pragma unroll
    for (int m = 0; m < 4; ++m) af[m] = *(const bf16x8*)&As[wr * 64 + m * 16 + c][g * 8];
#pragma unroll
    for (int n = 0; n < 4; ++n) bfr[n] = *(const bf16x8*)&Bs[wc * 64 + n * 16 + c][g * 8];
#pragma unroll
    for (int m = 0; m < 4; ++m)
#pragma unroll
      for (int n = 0; n < 4; ++n)
        acc[m][n] = __builtin_amdgcn_mfma_f32_16x16x32_bf16(af[m], bfr[n], acc[m][n], 0, 0, 0);
    __syncthreads();
  }

#pragma unroll
  for (int m = 0; m < 4; ++m)
#pragma unroll
    for (int n = 0; n < 4; ++n) {
      size_t row = rowBase + wr * 64 + m * 16 + g * 4;
      size_t col = colBase + wc * 64 + n * 16 + c;
#pragma unroll
      for (int r = 0; r < 4; ++r)
        storeC(&C[(row + r) * (size_t)N + col], acc[m][n][r]);
    }
}

// ---------------- RoPE on q,k; writes Q,K in [B,H,S,HD] --------------------
__global__ void rope_qk(const u16* __restrict__ qkv, const float* __restrict__ tab,
                        u16* __restrict__ Q, u16* __restrict__ K) {
  int idx = blockIdx.x * 256 + threadIdx.x;
  int j = idx & 63;
  int s = (idx >> 6) & (S_LEN - 1);
  int h = (idx >> 17) & (NH - 1);
  int b = idx >> 21;
  float cs = tab[s * 64 + j];
  float sn = tab[131072 + s * 64 + j];
  size_t qbase = (((size_t)(b * S_LEN + s) * 3 + 0) * NH + h) * HD;
  size_t kbase = qbase + (size_t)NH * HD;
  size_t o = ((size_t)(b * NH + h) * S_LEN + s) * HD;
  float q1 = bf2f(qkv[qbase + j]),  q2 = bf2f(qkv[qbase + j + 64]);
  Q[o + j]      = f2bf(q1 * cs - q2 * sn);
  Q[o + j + 64] = f2bf(q2 * cs + q1 * sn);
  float k1 = bf2f(qkv[kbase + j]), k2 = bf2f(qkv[kbase + j + 64]);
  K[o + j]      = f2bf(k1 * cs - k2 * sn);
  K[o + j + 64] = f2bf(k2 * cs + k1 * sn);
}

// ---------------- V transpose: qkv v-slot -> Vt [B,H,HD,S] -----------------
__global__ void v_transpose(const u16* __restrict__ qkv, u16* __restrict__ Vt) {
  __shared__ u16 t[32][33];
  int bh = blockIdx.z;
  int s0 = blockIdx.x * 32;
  int d0 = blockIdx.y * 32;
  int b = bh >> 4, h = bh & 15;
  int col = threadIdx.x & 31;
  int row = threadIdx.x >> 5;
#pragma unroll
  for (int i = 0; i < 4; ++i) {
    int s = row + i * 8;
    t[s][col] = qkv[(((size_t)(b * S_LEN + s0 + s) * 3 + 2) * NH + h) * HD + d0 + col];
  }
  __syncthreads();
  size_t vb = ((size_t)bh * HD + d0) * S_LEN + s0;
#pragma unroll
  for (int i = 0; i < 4; ++i) {
    int d = row + i * 8;
    Vt[vb + (size_t)d * S_LEN + col] = t[col][d];
  }
}

// ---------------- causal flash attention (swapped QK^T, balanced pairs) ----
// block = 2 waves; each wave owns 16 q-rows of tile qt, processes pair
// (pr, 127-pr) sequentially so all waves do identical total work.
// QK^T swapped: S^T = mfma(K_rows, Q_rows) -> q on lane axis (col=c),
// kv on (reg, g) axes -> row reductions are in-lane + 2 shfl.
__global__ __launch_bounds__(128) void attn_fwd(const u16* __restrict__ Q, const u16* __restrict__ K,
                                                const u16* __restrict__ Vt, u16* __restrict__ O) {
  __shared__ alignas(16) u16 P[2][16][72];  // +8 u16 pad: b64 writes ~2-way, b128 reads phase-optimal
  const int tid = threadIdx.x;
  const int lane = tid & 63;
  const int w = tid >> 6;
  const int g = lane >> 4, c = lane & 15;
  const int bh = blockIdx.y;
  const int b = bh >> 4, h = bh & 15;

  const u16* Qb = Q + (size_t)bh * S_LEN * HD;
  const u16* Kb = K + (size_t)bh * S_LEN * HD;
  const u16* Vb = Vt + (size_t)bh * HD * S_LEN;

  const int pr = blockIdx.x * 2 + w;  // 0..63
  const float SL = 0.12751753f;       // (1/sqrt(128)) * log2(e)

#pragma unroll 1
  for (int ph = 0; ph < 2; ++ph) {
    const int qt = ph ? (127 - pr) : pr;
    const int q0 = qt * 16;

    bf16x8 qf[4];
#pragma unroll
    for (int kb = 0; kb < 4; ++kb)
      qf[kb] = *(const bf16x8*)&Qb[(size_t)(q0 + c) * HD + kb * 32 + g * 8];

    f32x4 acc[8];
#pragma unroll
    for (int cb = 0; cb < 8; ++cb) acc[cb] = f32x4{0.f, 0.f, 0.f, 0.f};
    float m_i = -3e38f, l_i = 0.f;

    const int nsteps = (q0 + 16 + 63) >> 6;
#pragma unroll 1
    for (int st = 0; st < nsteps; ++st) {
      const int kv0 = st << 6;
      // ---- QK^T (swapped): s[t] = K[kv0+16t..][*] . Q^T, rows=kv, cols=q
      f32x4 s[4];
#pragma unroll
      for (int t = 0; t < 4; ++t) s[t] = f32x4{0.f, 0.f, 0.f, 0.f};
#pragma unroll
      for (int t = 0; t < 4; ++t)
#pragma unroll
        for (int kb = 0; kb < 4; ++kb) {
          bf16x8 kf = *(const bf16x8*)&Kb[(size_t)(kv0 + t * 16 + c) * HD + kb * 32 + g * 8];
          s[t] = __builtin_amdgcn_mfma_f32_16x16x32_bf16(kf, qf[kb], s[t], 0, 0, 0);
        }
      // ---- causal mask (kv = kv0+16t+4g+r must be <= qrow = q0+c)
      const int lim = q0 + c - kv0 - 4 * g;
#pragma unroll
      for (int t = 0; t < 4; ++t)
#pragma unroll
        for (int r = 0; r < 4; ++r)
          s[t][r] = (16 * t + r <= lim) ? s[t][r] : -3e38f;
      // ---- row max: in-lane over 16, then across g (2 shfl)
      float mx = s[0][0];
#pragma unroll
      for (int t = 0; t < 4; ++t)
#pragma unroll
        for (int r = 0; r < 4; ++r) mx = fmaxf(mx, s[t][r]);
      mx = fmaxf(mx, __shfl_xor(mx, 16));
      mx = fmaxf(mx, __shfl_xor(mx, 32));
      const float mn = fmaxf(m_i, mx);
      const float alpha = exp2f((m_i - mn) * SL);
      // ---- exp + row sum + pack P^T to LDS
      float rs = 0.f;
#pragma unroll
      for (int t = 0; t < 4; ++t) {
        ushort4 pw;
        float p0 = exp2f((s[t][0] - mn) * SL);
        float p1 = exp2f((s[t][1] - mn) * SL);
        float p2 = exp2f((s[t][2] - mn) * SL);
        float p3 = exp2f((s[t][3] - mn) * SL);
        rs += (p0 + p1) + (p2 + p3);
        pw.x = f2bf(p0); pw.y = f2bf(p1); pw.z = f2bf(p2); pw.w = f2bf(p3);
        *(ushort4*)&P[w][c][16 * t + 4 * g] = pw;
      }
      rs += __shfl_xor(rs, 16);
      rs += __shfl_xor(rs, 32);
      l_i = l_i * alpha + rs;
      m_i = mn;
      // ---- rescale acc by per-row alpha (rows live at lanes 4g+r)
      float ar[4];
#pragma unroll
      for (int r = 0; r < 4; ++r) ar[r] = __shfl(alpha, 4 * g + r);
#pragma unroll
      for (int cb = 0; cb < 8; ++cb)
#pragma unroll
        for (int r = 0; r < 4; ++r) acc[cb][r] *= ar[r];
      // ---- PV: A = P rows (q), B = Vt rows (d)
      bf16x8 pa0 = *(const bf16x8*)&P[w][c][g * 8];
      bf16x8 pa1 = *(const bf16x8*)&P[w][c][32 + g * 8];
#pragma unroll
      for (int cb = 0; cb < 8; ++cb) {
        bf16x8 vf0 = *(const bf16x8*)&Vb[(size_t)(cb * 16 + c) * S_LEN + kv0 + g * 8];
        acc[cb] = __builtin_amdgcn_mfma_f32_16x16x32_bf16(pa0, vf0, acc[cb], 0, 0, 0);
        bf16x8 vf1 = *(const bf16x8*)&Vb[(size_t)(cb * 16 + c) * S_LEN + kv0 + 32 + g * 8];
        acc[cb] = __builtin_amdgcn_mfma_f32_16x16x32_bf16(pa1, vf1, acc[cb], 0, 0, 0);
      }
    }
    // ---- epilogue: normalize, write O[b, q, h, d]
    float linv = 1.0f / l_i;
    float lr[4];
#pragma unroll
    for (int r = 0; r < 4; ++r) lr[r] = __shfl(linv, 4 * g + r);
#pragma unroll
    for (int cb = 0; cb < 8; ++cb)
#pragma unroll
      for (int r = 0; r < 4; ++r) {
        int q = q0 + 4 * g + r;
        O[(((size_t)b * S_LEN + q) * NH + h) * HD + cb * 16 + c] = f2bf(acc[cb][r] * lr[r]);
      }
  }
}

// ---------------------------------------------------------------------------
extern "C" void kernel_launch(void* const* d_in, const int* in_sizes, int n_in,
                              void* d_out, int out_size, void* d_ws, size_t ws_size,
                              hipStream_t stream) {
  const float* x    = (const float*)d_in[0];
  const float* wqkv = (const float*)d_in[1];
  const float* wo   = (const float*)d_in[2];
  float* out = (float*)d_out;
  char* ws = (char*)d_ws;

  u16*  xb    = (u16*)(ws + 0);            // reused as attn out later
  u16*  wqkvb = (u16*)(ws + 33554432);
  float* tab  = (float*)(ws + 58720256);   // unioned with wob (tab dead after rope)
  u16*  wob   = (u16*)(ws + 58720256);
  u16*  qkvb  = (u16*)(ws + 67108864);
  u16*  Vt    = (u16*)(ws + 167772160);
  u16*  attn  = (u16*)(ws + 0);
  u16*  Qr = (u16*)d_out;                  // d_out scratch: dead before GEMM2
  u16*  Kr = (u16*)d_out + 16777216;

  cvt_f32_bf16<<<16384, 256, 0, stream>>>(x, xb, 16777216 / 4);
  cvt_f32_bf16<<<12288, 256, 0, stream>>>(wqkv, wqkvb, 12582912 / 4);
  build_tab<<<512, 256, 0, stream>>>(tab);

  gemm_bt<u16><<<dim3(48, 64), 256, 0, stream>>>(xb, wqkvb, qkvb, 8192, 6144, 2048);

  rope_qk<<<32768, 256, 0, stream>>>(qkvb, tab, Qr, Kr);
  v_transpose<<<dim3(64, 4, 64), 256, 0, stream>>>(qkvb, Vt);

  cvt_f32_bf16<<<4096, 256, 0, stream>>>(wo, wob, 4194304 / 4);

  attn_fwd<<<dim3(32, 64), 128, 0, stream>>>(Qr, Kr, Vt, attn);

  gemm_bt<float><<<dim3(16, 64), 256, 0, stream>>>(attn, wob, out, 8192, 2048, 2048);
}

// Round 3
// 555.699 us; speedup vs baseline: 2.3574x; 1.8309x over previous
//
#include <hip/hip_runtime.h>

typedef unsigned short u16;
typedef unsigned int u32;
typedef __bf16 bf16x8 __attribute__((ext_vector_type(8)));
typedef float f32x4 __attribute__((ext_vector_type(4)));

#define S_LEN 2048
#define NH 16
#define HD 128

#define AS1 __attribute__((address_space(1)))
#define AS3 __attribute__((address_space(3)))

__device__ __forceinline__ u16 f2bf(float x) {
  u32 u = __builtin_bit_cast(u32, x);
  u32 r = u + 0x7FFFu + ((u >> 16) & 1u);  // RNE
  return (u16)(r >> 16);
}
__device__ __forceinline__ float bf2f(u16 b) {
  return __builtin_bit_cast(float, (u32)b << 16);
}

// ---------------- fp32 -> bf16 conversion (vectorized, G13) ----------------
__global__ void cvt_f32_bf16(const float* __restrict__ in, u16* __restrict__ out, int n4) {
  int i = blockIdx.x * 256 + threadIdx.x;
  if (i >= n4) return;
  float4 v = ((const float4*)in)[i];
  ushort4 o;
  o.x = f2bf(v.x); o.y = f2bf(v.y); o.z = f2bf(v.z); o.w = f2bf(v.w);
  ((ushort4*)out)[i] = o;
}

// ---------------- RoPE cos/sin table: tab[0..S*64) = cos, [S*64..) = sin ----
__global__ void build_tab(float* __restrict__ tab) {
  int t = blockIdx.x * 256 + threadIdx.x;
  int s = t >> 6, j = t & 63;
  float inv = exp2f(-(float)j * 0.20762050593045083f);
  float ang = (float)s * inv;
  tab[t] = cosf(ang);
  tab[131072 + t] = sinf(ang);
}

// ---------------- GEMM: C[M,N] = A[M,K] * B[N,K]^T, bf16 in, fp32 acc -------
__device__ __forceinline__ void storeC(u16* p, float v) { *p = f2bf(v); }
__device__ __forceinline__ void storeC(float* p, float v) { *p = v; }

template <typename OutT>
__global__ __launch_bounds__(256) void gemm_bt(const u16* __restrict__ A, const u16* __restrict__ B,
                                               OutT* __restrict__ C, int M, int N, int K) {
  __shared__ alignas(16) u16 As[128][32];
  __shared__ alignas(16) u16 Bs[128][32];
  const int tid = threadIdx.x;
  const int lane = tid & 63;
  const int w = tid >> 6;
  const int wr = w >> 1, wc = w & 1;
  const int g = lane >> 4, c = lane & 15;
  const size_t rowBase = (size_t)blockIdx.y * 128;
  const size_t colBase = (size_t)blockIdx.x * 128;

  f32x4 acc[4][4];
#pragma unroll
  for (int m = 0; m < 4; ++m)
#pragma unroll
    for (int n = 0; n < 4; ++n) acc[m][n] = f32x4{0.f, 0.f, 0.f, 0.f};

  const u16* Ag = A + rowBase * (size_t)K;
  const u16* Bg = B + colBase * (size_t)K;
  const int srow = lane >> 2;
  const int scol = (lane & 3) * 8;

  for (int k0 = 0; k0 < K; k0 += 32) {
#pragma unroll
    for (int p = 0; p < 2; ++p) {
      const int ch = w * 2 + p;
      const u16* ga = Ag + (size_t)(ch * 16 + srow) * K + k0 + scol;
      const u16* gb = Bg + (size_t)(ch * 16 + srow) * K + k0 + scol;
      __builtin_amdgcn_global_load_lds(
          (const AS1 void*)ga,
          (AS3 void*)((char*)&As[0][0] + ch * 1024), 16, 0, 0);
      __builtin_amdgcn_global_load_lds(
          (const AS1 void*)gb,
          (AS3 void*)((char*)&Bs[0][0] + ch * 1024), 16, 0, 0);
    }
    __syncthreads();
    bf16x8 af[4], bfr[4];
#pragma unroll
    for (int m = 0; m < 4; ++m) af[m] = *(const bf16x8*)&As[wr * 64 + m * 16 + c][g * 8];
#pragma unroll
    for (int n = 0; n < 4; ++n) bfr[n] = *(const bf16x8*)&Bs[wc * 64 + n * 16 + c][g * 8];
#pragma unroll
    for (int m = 0; m < 4; ++m)
#pragma unroll
      for (int n = 0; n < 4; ++n)
        acc[m][n] = __builtin_amdgcn_mfma_f32_16x16x32_bf16(af[m], bfr[n], acc[m][n], 0, 0, 0);
    __syncthreads();
  }

#pragma unroll
  for (int m = 0; m < 4; ++m)
#pragma unroll
    for (int n = 0; n < 4; ++n) {
      size_t row = rowBase + wr * 64 + m * 16 + g * 4;
      size_t col = colBase + wc * 64 + n * 16 + c;
#pragma unroll
      for (int r = 0; r < 4; ++r)
        storeC(&C[(row + r) * (size_t)N + col], acc[m][n][r]);
    }
}

// ---------------- RoPE on q,k; writes Q,K in [B,H,S,HD] --------------------
__global__ void rope_qk(const u16* __restrict__ qkv, const float* __restrict__ tab,
                        u16* __restrict__ Q, u16* __restrict__ K) {
  int idx = blockIdx.x * 256 + threadIdx.x;
  int j = idx & 63;
  int s = (idx >> 6) & (S_LEN - 1);
  int h = (idx >> 17) & (NH - 1);
  int b = idx >> 21;
  float cs = tab[s * 64 + j];
  float sn = tab[131072 + s * 64 + j];
  size_t qbase = (((size_t)(b * S_LEN + s) * 3 + 0) * NH + h) * HD;
  size_t kbase = qbase + (size_t)NH * HD;
  size_t o = ((size_t)(b * NH + h) * S_LEN + s) * HD;
  float q1 = bf2f(qkv[qbase + j]),  q2 = bf2f(qkv[qbase + j + 64]);
  Q[o + j]      = f2bf(q1 * cs - q2 * sn);
  Q[o + j + 64] = f2bf(q2 * cs + q1 * sn);
  float k1 = bf2f(qkv[kbase + j]), k2 = bf2f(qkv[kbase + j + 64]);
  K[o + j]      = f2bf(k1 * cs - k2 * sn);
  K[o + j + 64] = f2bf(k2 * cs + k1 * sn);
}

// ---------------- V transpose: qkv v-slot -> Vt [B,H,HD,S] -----------------
__global__ void v_transpose(const u16* __restrict__ qkv, u16* __restrict__ Vt) {
  __shared__ u16 t[32][33];
  int bh = blockIdx.z;
  int s0 = blockIdx.x * 32;
  int d0 = blockIdx.y * 32;
  int b = bh >> 4, h = bh & 15;
  int col = threadIdx.x & 31;
  int row = threadIdx.x >> 5;
#pragma unroll
  for (int i = 0; i < 4; ++i) {
    int s = row + i * 8;
    t[s][col] = qkv[(((size_t)(b * S_LEN + s0 + s) * 3 + 2) * NH + h) * HD + d0 + col];
  }
  __syncthreads();
  size_t vb = ((size_t)bh * HD + d0) * S_LEN + s0;
#pragma unroll
  for (int i = 0; i < 4; ++i) {
    int d = row + i * 8;
    Vt[vb + (size_t)d * S_LEN + col] = t[col][d];
  }
}

// ---------------- causal flash attention: 8-wave block, LDS-staged K/V -----
// Block owns (bh, 128 q-rows = supertile), processes pair (i, 15-i) for
// balance. Per 64-kv step: 8 waves co-stage K(16KB)+V(16KB) into dbuf LDS
// (global_load_lds w16, pre-swizzled source), swapped QK^T (q on lane axis),
// in-register softmax, P via swizzled wave-private LDS, PV from LDS V.
__global__ __launch_bounds__(512, 4) void attn_fwd(const u16* __restrict__ Q, const u16* __restrict__ K,
                                                   const u16* __restrict__ Vt, u16* __restrict__ O) {
  __shared__ alignas(16) u16 Ks[2 * 64 * 128];   // 32 KiB
  __shared__ alignas(16) u16 Vs[2 * 128 * 64];   // 32 KiB
  __shared__ alignas(16) u16 Pl[8 * 16 * 64];    // 16 KiB
  const int tid = threadIdx.x;
  const int lane = tid & 63;
  const int w = tid >> 6;
  const int g = lane >> 4, c = lane & 15;
  const int bh = blockIdx.x;      // fast dim -> pair-blocks of a bh share XCD
  const int pair = blockIdx.y;    // 0..7
  const int b = bh >> 4, h = bh & 15;

  const u16* Qb = Q + (size_t)bh * S_LEN * HD;
  const u16* Kb = K + (size_t)bh * S_LEN * HD;
  const u16* Vb = Vt + (size_t)bh * HD * S_LEN;
  const float SL = 0.12751753f;   // (1/sqrt(128)) * log2(e)
  const int swz = (c & 7) << 4;

  // staging constants: wave w issues instrs i=2w,2w+1 for K and V (1KB each)
  int ldsOff[2], srcK[2], srcV[2];
#pragma unroll
  for (int ii = 0; ii < 2; ++ii) {
    int p = (w * 2 + ii) * 1024 + lane * 16;  // linear byte slot in 16KB tile
    ldsOff[ii] = p;
    int rk = p >> 8, ik = p & 255;            // K tile: 64 rows x 256B
    srcK[ii] = rk * 256 + (ik ^ ((rk & 7) << 4));
    int rv = p >> 7, iv = p & 127;            // V tile: 128 rows x 128B
    srcV[ii] = rv * (S_LEN * 2) + (iv ^ ((rv & 7) << 4));
  }
  // per-lane read offsets (within-row, swizzled)
  int koff[4], voff[2];
#pragma unroll
  for (int kb = 0; kb < 4; ++kb) koff[kb] = (kb * 64 + g * 16) ^ swz;
  voff[0] = (g * 16) ^ swz;
  voff[1] = (64 + g * 16) ^ swz;
  int poff[4];
#pragma unroll
  for (int t = 0; t < 4; ++t) poff[t] = (t * 32 + g * 8) ^ swz;
  char* Pw = (char*)Pl + w * 2048;

#pragma unroll 1
  for (int ph = 0; ph < 2; ++ph) {
    const int sti = ph ? (15 - pair) : pair;
    const int qb0 = sti * 128;
    const int q0 = qb0 + w * 16;

    bf16x8 qf[4];
#pragma unroll
    for (int kb = 0; kb < 4; ++kb)
      qf[kb] = *(const bf16x8*)&Qb[(size_t)(q0 + c) * HD + kb * 32 + g * 8];

    f32x4 acc[8];
#pragma unroll
    for (int cb = 0; cb < 8; ++cb) acc[cb] = f32x4{0.f, 0.f, 0.f, 0.f};
    float m_i = -3e38f, l_i = 0.f;

    const int nsteps = sti * 2 + 2;
    // prologue: stage tile 0 into buf 0
#pragma unroll
    for (int ii = 0; ii < 2; ++ii) {
      __builtin_amdgcn_global_load_lds((const AS1 void*)((const char*)Kb + srcK[ii]),
                                       (AS3 void*)((char*)Ks + ldsOff[ii] - lane * 16), 16, 0, 0);
      __builtin_amdgcn_global_load_lds((const AS1 void*)((const char*)Vb + srcV[ii]),
                                       (AS3 void*)((char*)Vs + ldsOff[ii] - lane * 16), 16, 0, 0);
    }
    __syncthreads();
    int cur = 0;

#pragma unroll 1
    for (int st = 0; st < nsteps; ++st) {
      const int kv0 = st << 6;
      if (st + 1 < nsteps) {
        const char* kbase = (const char*)Kb + (size_t)(kv0 + 64) * 256;
        const char* vbase = (const char*)Vb + (size_t)(kv0 + 64) * 2;
        const int nb = (cur ^ 1) * 16384;
#pragma unroll
        for (int ii = 0; ii < 2; ++ii) {
          __builtin_amdgcn_global_load_lds((const AS1 void*)(kbase + srcK[ii]),
                                           (AS3 void*)((char*)Ks + nb + ldsOff[ii] - lane * 16), 16, 0, 0);
          __builtin_amdgcn_global_load_lds((const AS1 void*)(vbase + srcV[ii]),
                                           (AS3 void*)((char*)Vs + nb + ldsOff[ii] - lane * 16), 16, 0, 0);
        }
      }
      if (kv0 < q0 + 16) {
        const char* Kt = (const char*)Ks + cur * 16384;
        const char* Vtl = (const char*)Vs + cur * 16384;
        f32x4 s[4];
#pragma unroll
        for (int t = 0; t < 4; ++t) s[t] = f32x4{0.f, 0.f, 0.f, 0.f};
#pragma unroll
        for (int t = 0; t < 4; ++t)
#pragma unroll
          for (int kb = 0; kb < 4; ++kb) {
            bf16x8 kf = *(const bf16x8*)(Kt + t * 4096 + c * 256 + koff[kb]);
            s[t] = __builtin_amdgcn_mfma_f32_16x16x32_bf16(kf, qf[kb], s[t], 0, 0, 0);
          }
        if (kv0 + 63 > q0) {  // causal mask needed
          const int lim = q0 + c - kv0 - 4 * g;
#pragma unroll
          for (int t = 0; t < 4; ++t)
#pragma unroll
            for (int r = 0; r < 4; ++r)
              s[t][r] = (16 * t + r <= lim) ? s[t][r] : -3e38f;
        }
        // row max (q=c column): in-lane over 16, 2 shfl across groups
        float mx = s[0][0];
#pragma unroll
        for (int t = 0; t < 4; ++t)
#pragma unroll
          for (int r = 0; r < 4; ++r) mx = fmaxf(mx, s[t][r]);
        mx = fmaxf(mx, __shfl_xor(mx, 16));
        mx = fmaxf(mx, __shfl_xor(mx, 32));
        const float mn = fmaxf(m_i, mx);
        const float alpha = exp2f((m_i - mn) * SL);
        float rs = 0.f;
#pragma unroll
        for (int t = 0; t < 4; ++t) {
          float p0 = exp2f((s[t][0] - mn) * SL);
          float p1 = exp2f((s[t][1] - mn) * SL);
          float p2 = exp2f((s[t][2] - mn) * SL);
          float p3 = exp2f((s[t][3] - mn) * SL);
          rs += (p0 + p1) + (p2 + p3);
          ushort4 pw;
          pw.x = f2bf(p0); pw.y = f2bf(p1); pw.z = f2bf(p2); pw.w = f2bf(p3);
          *(ushort4*)(Pw + c * 128 + poff[t]) = pw;
        }
        rs += __shfl_xor(rs, 16);
        rs += __shfl_xor(rs, 32);
        l_i = l_i * alpha + rs;
        m_i = mn;
        float ar[4];
#pragma unroll
        for (int r = 0; r < 4; ++r) ar[r] = __shfl(alpha, 4 * g + r);
#pragma unroll
        for (int cb = 0; cb < 8; ++cb)
#pragma unroll
          for (int r = 0; r < 4; ++r) acc[cb][r] *= ar[r];
        bf16x8 pa0 = *(const bf16x8*)(Pw + c * 128 + voff[0]);
        bf16x8 pa1 = *(const bf16x8*)(Pw + c * 128 + voff[1]);
#pragma unroll
        for (int cb = 0; cb < 8; ++cb) {
          bf16x8 vf0 = *(const bf16x8*)(Vtl + cb * 2048 + c * 128 + voff[0]);
          acc[cb] = __builtin_amdgcn_mfma_f32_16x16x32_bf16(pa0, vf0, acc[cb], 0, 0, 0);
          bf16x8 vf1 = *(const bf16x8*)(Vtl + cb * 2048 + c * 128 + voff[1]);
          acc[cb] = __builtin_amdgcn_mfma_f32_16x16x32_bf16(pa1, vf1, acc[cb], 0, 0, 0);
        }
      }
      __syncthreads();
      cur ^= 1;
    }
    // epilogue: normalize, write O[b, q, h, d]
    float linv = 1.0f / l_i;
    float lr[4];
#pragma unroll
    for (int r = 0; r < 4; ++r) lr[r] = __shfl(linv, 4 * g + r);
#pragma unroll
    for (int cb = 0; cb < 8; ++cb)
#pragma unroll
      for (int r = 0; r < 4; ++r) {
        int q = q0 + 4 * g + r;
        O[(((size_t)b * S_LEN + q) * NH + h) * HD + cb * 16 + c] = f2bf(acc[cb][r] * lr[r]);
      }
  }
}

// ---------------------------------------------------------------------------
extern "C" void kernel_launch(void* const* d_in, const int* in_sizes, int n_in,
                              void* d_out, int out_size, void* d_ws, size_t ws_size,
                              hipStream_t stream) {
  const float* x    = (const float*)d_in[0];
  const float* wqkv = (const float*)d_in[1];
  const float* wo   = (const float*)d_in[2];
  float* out = (float*)d_out;
  char* ws = (char*)d_ws;

  u16*  xb    = (u16*)(ws + 0);            // reused as attn out later
  u16*  wqkvb = (u16*)(ws + 33554432);
  float* tab  = (float*)(ws + 58720256);   // unioned with wob (tab dead after rope)
  u16*  wob   = (u16*)(ws + 58720256);
  u16*  qkvb  = (u16*)(ws + 67108864);
  u16*  Vt    = (u16*)(ws + 167772160);
  u16*  attn  = (u16*)(ws + 0);
  u16*  Qr = (u16*)d_out;                  // d_out scratch: dead before GEMM2
  u16*  Kr = (u16*)d_out + 16777216;

  cvt_f32_bf16<<<16384, 256, 0, stream>>>(x, xb, 16777216 / 4);
  cvt_f32_bf16<<<12288, 256, 0, stream>>>(wqkv, wqkvb, 12582912 / 4);
  build_tab<<<512, 256, 0, stream>>>(tab);

  gemm_bt<u16><<<dim3(48, 64), 256, 0, stream>>>(xb, wqkvb, qkvb, 8192, 6144, 2048);

  rope_qk<<<32768, 256, 0, stream>>>(qkvb, tab, Qr, Kr);
  v_transpose<<<dim3(64, 4, 64), 256, 0, stream>>>(qkvb, Vt);

  cvt_f32_bf16<<<4096, 256, 0, stream>>>(wo, wob, 4194304 / 4);

  attn_fwd<<<dim3(64, 8), 512, 0, stream>>>(Qr, Kr, Vt, attn);

  gemm_bt<float><<<dim3(16, 64), 256, 0, stream>>>(attn, wob, out, 8192, 2048, 2048);
}

// Round 4
// 443.425 us; speedup vs baseline: 2.9543x; 1.2532x over previous
//
#include <hip/hip_runtime.h>

typedef unsigned short u16;
typedef unsigned int u32;
typedef __bf16 bf16x8 __attribute__((ext_vector_type(8)));
typedef float f32x4 __attribute__((ext_vector_type(4)));

#define S_LEN 2048
#define NH 16
#define HD 128

#define AS1 __attribute__((address_space(1)))
#define AS3 __attribute__((address_space(3)))

__device__ __forceinline__ u16 f2bf(float x) {
  u32 u = __builtin_bit_cast(u32, x);
  u32 r = u + 0x7FFFu + ((u >> 16) & 1u);  // RNE
  return (u16)(r >> 16);
}
__device__ __forceinline__ float bf2f(u16 b) {
  return __builtin_bit_cast(float, (u32)b << 16);
}

// ---------------- fp32 -> bf16 conversion (vectorized, G13) ----------------
__global__ void cvt_f32_bf16(const float* __restrict__ in, u16* __restrict__ out, int n4) {
  int i = blockIdx.x * 256 + threadIdx.x;
  if (i >= n4) return;
  float4 v = ((const float4*)in)[i];
  ushort4 o;
  o.x = f2bf(v.x); o.y = f2bf(v.y); o.z = f2bf(v.z); o.w = f2bf(v.w);
  ((ushort4*)out)[i] = o;
}

// ---------------- RoPE cos/sin table: tab[0..S*64) = cos, [S*64..) = sin ----
__global__ void build_tab(float* __restrict__ tab) {
  int t = blockIdx.x * 256 + threadIdx.x;
  int s = t >> 6, j = t & 63;
  float inv = exp2f(-(float)j * 0.20762050593045083f);
  float ang = (float)s * inv;
  tab[t] = cosf(ang);
  tab[131072 + t] = sinf(ang);
}

// ---------------- GEMM: C[M,N] = A[M,K]*B[N,K]^T -----------------------------
// 256x256 tile, BK=32, 8 waves (2x4), ring-4 LDS buffers (128 KiB),
// counted vmcnt(4) across raw barriers (T3+T4), 2-way-max LDS swizzle (T2),
// setprio around MFMA clusters (T5), bijective XCD block swizzle (T1).
__device__ __forceinline__ void storeC(u16* p, float v) { *p = f2bf(v); }
__device__ __forceinline__ void storeC(float* p, float v) { *p = v; }

template <typename OutT>
__global__ __launch_bounds__(512, 2) void gemm_bt2(const u16* __restrict__ A, const u16* __restrict__ B,
                                                   OutT* __restrict__ C, int M, int N, int K, int nbx) {
  __shared__ alignas(16) u16 LDS[65536];  // 4 bufs x (A 16KB + B 16KB) = 128 KiB
  char* lds = (char*)LDS;
  const int tid = threadIdx.x;
  const int lane = tid & 63;
  const int w = tid >> 6;              // 0..7
  const int wr = w >> 2, wc = w & 3;   // 2 x 4 wave grid
  const int g = lane >> 4, c = lane & 15;

  // XCD-aware bijective swizzle (nwg multiple of 8)
  const int nwg = gridDim.x;
  const int id = blockIdx.x;
  const int sw = (id & 7) * (nwg >> 3) + (id >> 3);
  const int bx = sw % nbx, by = sw / nbx;
  const size_t rowBase = (size_t)by * 256;
  const size_t colBase = (size_t)bx * 256;

  const char* Ap = (const char*)(A + rowBase * (size_t)K);
  const char* Bp = (const char*)(B + colBase * (size_t)K);

  // staging slots: thread covers 2 x 16B for A and same for B per K-tile.
  // LDS layout per region: [256 rows][4 chunks of 16B], chunk swizzled by
  // T(row) = (row ^ (row>>2)) & 3 : physical chunk = logical ^ T (involution).
  // global_load_lds writes linearly -> inverse-swizzle the per-lane SOURCE.
  int dstOff[2], srcO[2];
#pragma unroll
  for (int s = 0; s < 2; ++s) {
    int base = (w * 2 + s) * 1024;
    dstOff[s] = base;
    int L = base + lane * 16;
    int row = L >> 6;
    int pc = (L >> 4) & 3;
    int T = (row ^ (row >> 2)) & 3;
    srcO[s] = row * (K * 2) + ((pc ^ T) << 4);
  }
  // swizzled read offsets (2-way max bank aliasing = free)
  int aoff[8], boff[4];
#pragma unroll
  for (int m = 0; m < 8; ++m) {
    int row = wr * 128 + m * 16 + c;
    int T = (row ^ (row >> 2)) & 3;
    aoff[m] = row * 64 + ((g ^ T) << 4);
  }
#pragma unroll
  for (int n = 0; n < 4; ++n) {
    int row = wc * 64 + n * 16 + c;
    int T = (row ^ (row >> 2)) & 3;
    boff[n] = row * 64 + ((g ^ T) << 4);
  }

  f32x4 acc[8][4];
#pragma unroll
  for (int m = 0; m < 8; ++m)
#pragma unroll
    for (int n = 0; n < 4; ++n) acc[m][n] = f32x4{0.f, 0.f, 0.f, 0.f};

  const int NT = K >> 5;

  auto stage = [&](int tt, int s) {
    const int bufb = (tt & 3) * 32768;
    const int kb = tt * 64;  // k0 * 2 bytes
    __builtin_amdgcn_global_load_lds((const AS1 void*)(Ap + srcO[s] + kb),
                                     (AS3 void*)(lds + bufb + dstOff[s]), 16, 0, 0);
    __builtin_amdgcn_global_load_lds((const AS1 void*)(Bp + srcO[s] + kb),
                                     (AS3 void*)(lds + bufb + 16384 + dstOff[s]), 16, 0, 0);
  };

  // prologue: stage tiles 0 and 1 (8 loads), wait tile 0 (leave 4 in flight)
  stage(0, 0); stage(0, 1);
  stage(1, 0); stage(1, 1);
  asm volatile("s_waitcnt vmcnt(4)" ::: "memory");
  __builtin_amdgcn_s_barrier();

#pragma unroll 1
  for (int t = 0; t < NT; ++t) {
    const char* bufA = lds + (t & 3) * 32768;
    const char* bufB = bufA + 16384;
    bf16x8 aF[4], bF[4];
    // ---- phase A: quadrant m0..3 (8 ds_read_b128) + stage slot 0 of t+2
#pragma unroll
    for (int m = 0; m < 4; ++m) aF[m] = *(const bf16x8*)(bufA + aoff[m]);
#pragma unroll
    for (int n = 0; n < 4; ++n) bF[n] = *(const bf16x8*)(bufB + boff[n]);
    if (t + 2 < NT) stage(t + 2, 0);
    asm volatile("s_waitcnt lgkmcnt(0)" ::: "memory");
    __builtin_amdgcn_sched_barrier(0);
    __builtin_amdgcn_s_setprio(1);
#pragma unroll
    for (int m = 0; m < 4; ++m)
#pragma unroll
      for (int n = 0; n < 4; ++n)
        acc[m][n] = __builtin_amdgcn_mfma_f32_16x16x32_bf16(aF[m], bF[n], acc[m][n], 0, 0, 0);
    __builtin_amdgcn_s_setprio(0);
    __builtin_amdgcn_sched_barrier(0);
    __builtin_amdgcn_s_barrier();
    // ---- phase B: quadrant m4..7 (4 ds_read_b128, bF reused) + stage slot 1
#pragma unroll
    for (int m = 0; m < 4; ++m) aF[m] = *(const bf16x8*)(bufA + aoff[4 + m]);
    if (t + 2 < NT) stage(t + 2, 1);
    asm volatile("s_waitcnt lgkmcnt(0)" ::: "memory");
    __builtin_amdgcn_sched_barrier(0);
    __builtin_amdgcn_s_setprio(1);
#pragma unroll
    for (int m = 0; m < 4; ++m)
#pragma unroll
      for (int n = 0; n < 4; ++n)
        acc[4 + m][n] = __builtin_amdgcn_mfma_f32_16x16x32_bf16(aF[m], bF[n], acc[4 + m][n], 0, 0, 0);
    __builtin_amdgcn_s_setprio(0);
    __builtin_amdgcn_sched_barrier(0);
    // ---- tile boundary: counted wait (tile t+1 landed; t+2's 4 stay in flight)
    if (t + 2 < NT) { asm volatile("s_waitcnt vmcnt(4)" ::: "memory"); }
    else            { asm volatile("s_waitcnt vmcnt(0)" ::: "memory"); }
    __builtin_amdgcn_s_barrier();
  }

  // epilogue
#pragma unroll
  for (int m = 0; m < 8; ++m)
#pragma unroll
    for (int n = 0; n < 4; ++n) {
      size_t row = rowBase + wr * 128 + m * 16 + g * 4;
      size_t col = colBase + wc * 64 + n * 16 + c;
#pragma unroll
      for (int r = 0; r < 4; ++r)
        storeC(&C[(row + r) * (size_t)N + col], acc[m][n][r]);
    }
}

// ---------------- RoPE on q,k; writes Q,K in [B,H,S,HD] --------------------
__global__ void rope_qk(const u16* __restrict__ qkv, const float* __restrict__ tab,
                        u16* __restrict__ Q, u16* __restrict__ K) {
  int idx = blockIdx.x * 256 + threadIdx.x;
  int j = idx & 63;
  int s = (idx >> 6) & (S_LEN - 1);
  int h = (idx >> 17) & (NH - 1);
  int b = idx >> 21;
  float cs = tab[s * 64 + j];
  float sn = tab[131072 + s * 64 + j];
  size_t qbase = (((size_t)(b * S_LEN + s) * 3 + 0) * NH + h) * HD;
  size_t kbase = qbase + (size_t)NH * HD;
  size_t o = ((size_t)(b * NH + h) * S_LEN + s) * HD;
  float q1 = bf2f(qkv[qbase + j]),  q2 = bf2f(qkv[qbase + j + 64]);
  Q[o + j]      = f2bf(q1 * cs - q2 * sn);
  Q[o + j + 64] = f2bf(q2 * cs + q1 * sn);
  float k1 = bf2f(qkv[kbase + j]), k2 = bf2f(qkv[kbase + j + 64]);
  K[o + j]      = f2bf(k1 * cs - k2 * sn);
  K[o + j + 64] = f2bf(k2 * cs + k1 * sn);
}

// ---------------- V transpose: qkv v-slot -> Vt [B,H,HD,S] -----------------
__global__ void v_transpose(const u16* __restrict__ qkv, u16* __restrict__ Vt) {
  __shared__ u16 t[32][33];
  int bh = blockIdx.z;
  int s0 = blockIdx.x * 32;
  int d0 = blockIdx.y * 32;
  int b = bh >> 4, h = bh & 15;
  int col = threadIdx.x & 31;
  int row = threadIdx.x >> 5;
#pragma unroll
  for (int i = 0; i < 4; ++i) {
    int s = row + i * 8;
    t[s][col] = qkv[(((size_t)(b * S_LEN + s0 + s) * 3 + 2) * NH + h) * HD + d0 + col];
  }
  __syncthreads();
  size_t vb = ((size_t)bh * HD + d0) * S_LEN + s0;
#pragma unroll
  for (int i = 0; i < 4; ++i) {
    int d = row + i * 8;
    Vt[vb + (size_t)d * S_LEN + col] = t[col][d];
  }
}

// ---------------- causal flash attention: 8-wave block, LDS-staged K/V -----
__global__ __launch_bounds__(512, 4) void attn_fwd(const u16* __restrict__ Q, const u16* __restrict__ K,
                                                   const u16* __restrict__ Vt, u16* __restrict__ O) {
  __shared__ alignas(16) u16 Ks[2 * 64 * 128];
  __shared__ alignas(16) u16 Vs[2 * 128 * 64];
  __shared__ alignas(16) u16 Pl[8 * 16 * 64];
  const int tid = threadIdx.x;
  const int lane = tid & 63;
  const int w = tid >> 6;
  const int g = lane >> 4, c = lane & 15;
  const int bh = blockIdx.x;
  const int pair = blockIdx.y;
  const int b = bh >> 4, h = bh & 15;

  const u16* Qb = Q + (size_t)bh * S_LEN * HD;
  const u16* Kb = K + (size_t)bh * S_LEN * HD;
  const u16* Vb = Vt + (size_t)bh * HD * S_LEN;
  const float SL = 0.12751753f;
  const int swz = (c & 7) << 4;

  int ldsOff[2], srcK[2], srcV[2];
#pragma unroll
  for (int ii = 0; ii < 2; ++ii) {
    int p = (w * 2 + ii) * 1024 + lane * 16;
    ldsOff[ii] = p;
    int rk = p >> 8, ik = p & 255;
    srcK[ii] = rk * 256 + (ik ^ ((rk & 7) << 4));
    int rv = p >> 7, iv = p & 127;
    srcV[ii] = rv * (S_LEN * 2) + (iv ^ ((rv & 7) << 4));
  }
  int koff[4], voff[2];
#pragma unroll
  for (int kb = 0; kb < 4; ++kb) koff[kb] = (kb * 64 + g * 16) ^ swz;
  voff[0] = (g * 16) ^ swz;
  voff[1] = (64 + g * 16) ^ swz;
  int poff[4];
#pragma unroll
  for (int t = 0; t < 4; ++t) poff[t] = (t * 32 + g * 8) ^ swz;
  char* Pw = (char*)Pl + w * 2048;

#pragma unroll 1
  for (int ph = 0; ph < 2; ++ph) {
    const int sti = ph ? (15 - pair) : pair;
    const int qb0 = sti * 128;
    const int q0 = qb0 + w * 16;

    bf16x8 qf[4];
#pragma unroll
    for (int kb = 0; kb < 4; ++kb)
      qf[kb] = *(const bf16x8*)&Qb[(size_t)(q0 + c) * HD + kb * 32 + g * 8];

    f32x4 acc[8];
#pragma unroll
    for (int cb = 0; cb < 8; ++cb) acc[cb] = f32x4{0.f, 0.f, 0.f, 0.f};
    float m_i = -3e38f, l_i = 0.f;

    const int nsteps = sti * 2 + 2;
#pragma unroll
    for (int ii = 0; ii < 2; ++ii) {
      __builtin_amdgcn_global_load_lds((const AS1 void*)((const char*)Kb + srcK[ii]),
                                       (AS3 void*)((char*)Ks + ldsOff[ii] - lane * 16), 16, 0, 0);
      __builtin_amdgcn_global_load_lds((const AS1 void*)((const char*)Vb + srcV[ii]),
                                       (AS3 void*)((char*)Vs + ldsOff[ii] - lane * 16), 16, 0, 0);
    }
    __syncthreads();
    int cur = 0;

#pragma unroll 1
    for (int st = 0; st < nsteps; ++st) {
      const int kv0 = st << 6;
      if (st + 1 < nsteps) {
        const char* kbase = (const char*)Kb + (size_t)(kv0 + 64) * 256;
        const char* vbase = (const char*)Vb + (size_t)(kv0 + 64) * 2;
        const int nb = (cur ^ 1) * 16384;
#pragma unroll
        for (int ii = 0; ii < 2; ++ii) {
          __builtin_amdgcn_global_load_lds((const AS1 void*)(kbase + srcK[ii]),
                                           (AS3 void*)((char*)Ks + nb + ldsOff[ii] - lane * 16), 16, 0, 0);
          __builtin_amdgcn_global_load_lds((const AS1 void*)(vbase + srcV[ii]),
                                           (AS3 void*)((char*)Vs + nb + ldsOff[ii] - lane * 16), 16, 0, 0);
        }
      }
      if (kv0 < q0 + 16) {
        const char* Kt = (const char*)Ks + cur * 16384;
        const char* Vtl = (const char*)Vs + cur * 16384;
        f32x4 s[4];
#pragma unroll
        for (int t = 0; t < 4; ++t) s[t] = f32x4{0.f, 0.f, 0.f, 0.f};
#pragma unroll
        for (int t = 0; t < 4; ++t)
#pragma unroll
          for (int kb = 0; kb < 4; ++kb) {
            bf16x8 kf = *(const bf16x8*)(Kt + t * 4096 + c * 256 + koff[kb]);
            s[t] = __builtin_amdgcn_mfma_f32_16x16x32_bf16(kf, qf[kb], s[t], 0, 0, 0);
          }
        if (kv0 + 63 > q0) {
          const int lim = q0 + c - kv0 - 4 * g;
#pragma unroll
          for (int t = 0; t < 4; ++t)
#pragma unroll
            for (int r = 0; r < 4; ++r)
              s[t][r] = (16 * t + r <= lim) ? s[t][r] : -3e38f;
        }
        float mx = s[0][0];
#pragma unroll
        for (int t = 0; t < 4; ++t)
#pragma unroll
          for (int r = 0; r < 4; ++r) mx = fmaxf(mx, s[t][r]);
        mx = fmaxf(mx, __shfl_xor(mx, 16));
        mx = fmaxf(mx, __shfl_xor(mx, 32));
        const float mn = fmaxf(m_i, mx);
        const float alpha = exp2f((m_i - mn) * SL);
        float rs = 0.f;
#pragma unroll
        for (int t = 0; t < 4; ++t) {
          float p0 = exp2f((s[t][0] - mn) * SL);
          float p1 = exp2f((s[t][1] - mn) * SL);
          float p2 = exp2f((s[t][2] - mn) * SL);
          float p3 = exp2f((s[t][3] - mn) * SL);
          rs += (p0 + p1) + (p2 + p3);
          ushort4 pw;
          pw.x = f2bf(p0); pw.y = f2bf(p1); pw.z = f2bf(p2); pw.w = f2bf(p3);
          *(ushort4*)(Pw + c * 128 + poff[t]) = pw;
        }
        rs += __shfl_xor(rs, 16);
        rs += __shfl_xor(rs, 32);
        l_i = l_i * alpha + rs;
        m_i = mn;
        float ar[4];
#pragma unroll
        for (int r = 0; r < 4; ++r) ar[r] = __shfl(alpha, 4 * g + r);
#pragma unroll
        for (int cb = 0; cb < 8; ++cb)
#pragma unroll
          for (int r = 0; r < 4; ++r) acc[cb][r] *= ar[r];
        bf16x8 pa0 = *(const bf16x8*)(Pw + c * 128 + voff[0]);
        bf16x8 pa1 = *(const bf16x8*)(Pw + c * 128 + voff[1]);
#pragma unroll
        for (int cb = 0; cb < 8; ++cb) {
          bf16x8 vf0 = *(const bf16x8*)(Vtl + cb * 2048 + c * 128 + voff[0]);
          acc[cb] = __builtin_amdgcn_mfma_f32_16x16x32_bf16(pa0, vf0, acc[cb], 0, 0, 0);
          bf16x8 vf1 = *(const bf16x8*)(Vtl + cb * 2048 + c * 128 + voff[1]);
          acc[cb] = __builtin_amdgcn_mfma_f32_16x16x32_bf16(pa1, vf1, acc[cb], 0, 0, 0);
        }
      }
      __syncthreads();
      cur ^= 1;
    }
    float linv = 1.0f / l_i;
    float lr[4];
#pragma unroll
    for (int r = 0; r < 4; ++r) lr[r] = __shfl(linv, 4 * g + r);
#pragma unroll
    for (int cb = 0; cb < 8; ++cb)
#pragma unroll
      for (int r = 0; r < 4; ++r) {
        int q = q0 + 4 * g + r;
        O[(((size_t)b * S_LEN + q) * NH + h) * HD + cb * 16 + c] = f2bf(acc[cb][r] * lr[r]);
      }
  }
}

// ---------------------------------------------------------------------------
extern "C" void kernel_launch(void* const* d_in, const int* in_sizes, int n_in,
                              void* d_out, int out_size, void* d_ws, size_t ws_size,
                              hipStream_t stream) {
  const float* x    = (const float*)d_in[0];
  const float* wqkv = (const float*)d_in[1];
  const float* wo   = (const float*)d_in[2];
  float* out = (float*)d_out;
  char* ws = (char*)d_ws;

  u16*  xb    = (u16*)(ws + 0);            // reused as attn out later
  u16*  wqkvb = (u16*)(ws + 33554432);
  float* tab  = (float*)(ws + 58720256);   // unioned with wob (tab dead after rope)
  u16*  wob   = (u16*)(ws + 58720256);
  u16*  qkvb  = (u16*)(ws + 67108864);
  u16*  Vt    = (u16*)(ws + 167772160);
  u16*  attn  = (u16*)(ws + 0);
  u16*  Qr = (u16*)d_out;                  // d_out scratch: dead before GEMM2
  u16*  Kr = (u16*)d_out + 16777216;

  cvt_f32_bf16<<<16384, 256, 0, stream>>>(x, xb, 16777216 / 4);
  cvt_f32_bf16<<<12288, 256, 0, stream>>>(wqkv, wqkvb, 12582912 / 4);
  build_tab<<<512, 256, 0, stream>>>(tab);

  // qkv = x @ wqkv^T : M=8192, N=6144, K=2048 -> 24x32 = 768 blocks
  gemm_bt2<u16><<<768, 512, 0, stream>>>(xb, wqkvb, qkvb, 8192, 6144, 2048, 24);

  rope_qk<<<32768, 256, 0, stream>>>(qkvb, tab, Qr, Kr);
  v_transpose<<<dim3(64, 4, 64), 256, 0, stream>>>(qkvb, Vt);

  cvt_f32_bf16<<<4096, 256, 0, stream>>>(wo, wob, 4194304 / 4);

  attn_fwd<<<dim3(64, 8), 512, 0, stream>>>(Qr, Kr, Vt, attn);

  // out = attn @ wo^T : M=8192, N=2048, K=2048 -> 8x32 = 256 blocks
  gemm_bt2<float><<<256, 512, 0, stream>>>(attn, wob, out, 8192, 2048, 2048, 8);
}